// Round 1
// baseline (386.610 us; speedup 1.0000x reference)
//
#include <hip/hip_runtime.h>

#define HOUT 15
#define WOUT 15
// input  (32, 32, 32, 32, 16)  fp32
// ncv    (32, 32, 15, 15, 16)  fp32
// w      (3, 3, 32, 4, 4, 32)  fp32
// out    (32, 32, 15, 15, 16)  fp32

typedef float v2 __attribute__((ext_vector_type(2)));

// DPP butterfly add step (ctrl must be a literal)
#define DPP_ADDF(x, ctrl) \
    ((x) + __builtin_bit_cast(float, __builtin_amdgcn_update_dpp( \
        0, __builtin_bit_cast(int, (x)), (ctrl), 0xF, 0xF, true)))

// ---------------- pass 0: transpose w (d <-> m) -----------------------------
// w[kl][n][x][d][m]  ->  w2[n][kl][x][m][d]   (147456 floats = 576 KB)
// so each lane m reads {w[x,0..3,m]} as one float4, coalesced across lanes.
__global__ __launch_bounds__(256) void prep_w(const float* __restrict__ wt,
                                              float* __restrict__ w2)
{
    const int t  = blockIdx.x * 256 + threadIdx.x;   // dest index, 0..147455
    const int d  = t & 3;
    const int m  = (t >> 2) & 31;
    const int x  = (t >> 7) & 3;
    const int r  = t >> 9;        // n*9 + kl
    const int kl = r % 9;
    const int n  = r / 9;
    w2[t] = wt[((((kl * 32 + n) * 4 + x) * 4 + d) * 32) + m];
}

// ---------------- fused: attention + accumulate + LayerNorm ----------------
// One 32-lane group per output position (b,h,w); lane = m. 4 groups / block.
// No LDS, no barriers: w read directly via L1/L2 (18 KB per-n slice, cached).
// Grid fully resident (1800 blocks x 2 waves <= 4 waves/SIMD VGPR cap).
__global__ __launch_bounds__(128, 4) void caps_fused(
    const float* __restrict__ input,
    const float* __restrict__ ncv,
    const float* __restrict__ w2,
    const float* __restrict__ gamma,
    const float* __restrict__ beta,
    float* __restrict__ out)
{
    const int tid  = threadIdx.x;
    const int grp  = tid >> 5;      // 0..3
    const int lane = tid & 31;      // m

    const int pos = blockIdx.x * 4 + grp;      // 0..7199
    const int b   = pos / (HOUT * WOUT);
    const int hw  = pos % (HOUT * WOUT);
    const int h   = hw / WOUT;
    const int wo  = hw % WOUT;
    const int h0  = h * 2, w0 = wo * 2;

    // ncv[b, m=lane, h, wo, 0..15] as 8 x float2
    const float* ncv_p = ncv + ((((size_t)b * 32 + lane) * HOUT + h) * WOUT + wo) * 16;
    v2 cv2[8];
#pragma unroll
    for (int j = 0; j < 8; ++j) cv2[j] = *(const v2*)(ncv_p + j * 2);

    v2 acc2[8];
#pragma unroll
    for (int j = 0; j < 8; ++j) acc2[j] = (v2){0.0f, 0.0f};

    const float* ip0 = input + ((((size_t)b * 32) * 32 + h0) * 32 + w0) * 16;
    const float* wp0 = w2 + lane * 4;

    for (int n = 0; n < 32; ++n) {
        const float* ipn = ip0 + (size_t)n * 16384;        // 32*32*16
        const float* wpn = wp0 + (size_t)n * 4608;         // 9*4*128

#pragma unroll
        for (int kl = 0; kl < 9; ++kl) {
            const int k = kl / 3, l = kl % 3;
            const float* ip = ipn + (k * 32 + l) * 16;

            float av[16];
#pragma unroll
            for (int j = 0; j < 16; j += 4) {
                float4 t4 = *(const float4*)(ip + j);
                av[j] = t4.x; av[j + 1] = t4.y; av[j + 2] = t4.z; av[j + 3] = t4.w;
            }

            // w[x][0..3][m] for this (n,kl): 4 coalesced float4 loads
            const float* wp = wpn + kl * 512;
            float4 wx[4];
#pragma unroll
            for (int x = 0; x < 4; ++x) wx[x] = *(const float4*)(wp + x * 128);

            // u[a,d] = sum_x av[a,x] * w[x,d,m]; packed d-pairs
            v2 u2[8];
#pragma unroll
            for (int x = 0; x < 4; ++x) {
                v2 wlo = {wx[x].x, wx[x].y};
                v2 whi = {wx[x].z, wx[x].w};
#pragma unroll
                for (int a = 0; a < 4; ++a) {
                    v2 sp = {av[a * 4 + x], av[a * 4 + x]};
                    if (x == 0) {
                        u2[a * 2]     = sp * wlo;       // pk_mul: no zero-init
                        u2[a * 2 + 1] = sp * whi;
                    } else {
                        u2[a * 2]     = __builtin_elementwise_fma(sp, wlo, u2[a * 2]);
                        u2[a * 2 + 1] = __builtin_elementwise_fma(sp, whi, u2[a * 2 + 1]);
                    }
                }
            }

            // logit = 0.25 * <u, cv>;  e = exp(logit) = exp2(dot * 0.25*log2e)
            v2 d0 = {0.f, 0.f}, d1 = {0.f, 0.f};
#pragma unroll
            for (int j = 0; j < 4; ++j) {
                d0 = __builtin_elementwise_fma(u2[j],     cv2[j],     d0);
                d1 = __builtin_elementwise_fma(u2[j + 4], cv2[j + 4], d1);
            }
            v2 dd = d0 + d1;
            float e = __builtin_exp2f((dd.x + dd.y) * 0.36067376022224085f);

            // sum over 32 lanes (m): 4 DPP adds + 1 swizzle (xor16)
            // post-xor2 quads are uniform, so half_mirror==xor4, mirror==xor8
            float s = e;
            s = DPP_ADDF(s, 0xB1);    // quad_perm [1,0,3,2]  == xor1
            s = DPP_ADDF(s, 0x4E);    // quad_perm [2,3,0,1]  == xor2
            s = DPP_ADDF(s, 0x141);   // row_half_mirror      == xor4 here
            s = DPP_ADDF(s, 0x140);   // row_mirror           == xor8 here
            s += __builtin_bit_cast(float,
                  __builtin_amdgcn_ds_swizzle(__builtin_bit_cast(int, s), 0x401F)); // xor16

            float p = e * __builtin_amdgcn_rcpf(s);
            v2 p2 = {p, p};
#pragma unroll
            for (int j = 0; j < 8; ++j)
                acc2[j] = __builtin_elementwise_fma(p2, u2[j], acc2[j]);
        }
    }

    // ---- in-register LayerNorm over the 16 outputs this lane owns ----
    v2 sv = acc2[0];
#pragma unroll
    for (int j = 1; j < 8; ++j) sv = sv + acc2[j];
    float mu = (sv.x + sv.y) * 0.0625f;
    v2 mv = {mu, mu};
    v2 vv = {0.f, 0.f};
#pragma unroll
    for (int j = 0; j < 8; ++j) {
        v2 dlt = acc2[j] - mv;
        vv = __builtin_elementwise_fma(dlt, dlt, vv);
    }
    float var  = (vv.x + vv.y) * 0.0625f;
    float rstd = __builtin_amdgcn_rsqf(var + 1e-5f);

    float* op = out + ((((size_t)b * 32 + lane) * HOUT + h) * WOUT + wo) * 16;
#pragma unroll
    for (int j = 0; j < 4; ++j) {
        float4 g  = *(const float4*)(gamma + j * 4);
        float4 be = *(const float4*)(beta  + j * 4);
        float4 r;
        r.x = (acc2[2 * j].x     - mu) * rstd * g.x + be.x;
        r.y = (acc2[2 * j].y     - mu) * rstd * g.y + be.y;
        r.z = (acc2[2 * j + 1].x - mu) * rstd * g.z + be.z;
        r.w = (acc2[2 * j + 1].y - mu) * rstd * g.w + be.w;
        *(float4*)(op + j * 4) = r;
    }
}

extern "C" void kernel_launch(void* const* d_in, const int* in_sizes, int n_in,
                              void* d_out, int out_size, void* d_ws, size_t ws_size,
                              hipStream_t stream) {
    const float* input = (const float*)d_in[0];
    const float* ncv   = (const float*)d_in[1];
    const float* wt    = (const float*)d_in[2];
    const float* gamma = (const float*)d_in[3];
    const float* beta  = (const float*)d_in[4];
    float* out = (float*)d_out;
    float* w2  = (float*)d_ws;                 // 576 KB of workspace

    prep_w<<<dim3(576), dim3(256), 0, stream>>>(wt, w2);
    caps_fused<<<dim3(1800), dim3(128), 0, stream>>>(input, ncv, w2, gamma, beta, out);
}